// Round 4
// baseline (156.903 us; speedup 1.0000x reference)
//
#include <hip/hip_runtime.h>
#include <hip/hip_cooperative_groups.h>
#include <math.h>

namespace cg = cooperative_groups;

#define BATCH 128
#define N_IN 2048
#define N_OUT 1024
#define MAXK 40
#define TEMP 0.1f
#define INV_TEMP 10.0f
#define NEG_FILL -1.0e9f

__device__ __forceinline__ unsigned int f2key(float f) {
    unsigned int b = __float_as_uint(f);
    return (b & 0x80000000u) ? ~b : (b | 0x80000000u);
}
__device__ __forceinline__ float key2f(unsigned int u) {
    unsigned int b = (u & 0x80000000u) ? (u & 0x7FFFFFFFu) : ~u;
    return __uint_as_float(b);
}

// Single cooperative kernel, grid = N_OUT + BATCH blocks of 256.
//   blocks [0, N_OUT):       phase 1: compact active synapses of row o into LDS
//   blocks [N_OUT, +BATCH):  phase 1: exact lower-median of x row b (radix
//                            select), write gated x TRANSPOSED to gxT[i][b]
//   grid.sync()
//   blocks [0, N_OUT):       phase 2: out[b][o] for b = tid < 128 via sparse
//                            online logsumexp; gxT gathers are coalesced.
__global__ __launch_bounds__(256, 5) void k_all(const float* __restrict__ x,
                                                const float* __restrict__ w,
                                                const float* __restrict__ msk,
                                                float* __restrict__ gxT,
                                                float* __restrict__ out) {
    __shared__ unsigned int hist[256];
    __shared__ unsigned int wsum4[4];
    __shared__ unsigned int sel[2];
    __shared__ int s_cnt;
    __shared__ int2 slist[MAXK];

    const int tid = threadIdx.x;
    const int lane = tid & 63;
    const int wwid = tid >> 6;
    const int bid = (int)blockIdx.x;

    if (bid < N_OUT) {
        // ---------------- phase 1a: compaction into LDS ----------------
        const int o = bid;
        const float4* wr = (const float4*)(w + (size_t)o * N_IN);
        const float4* mr = (const float4*)(msk + (size_t)o * N_IN);
        float4 wa = wr[tid], wb = wr[tid + 256];
        float4 ma = mr[tid], mb = mr[tid + 256];
        float wv[8] = {wa.x, wa.y, wa.z, wa.w, wb.x, wb.y, wb.z, wb.w};
        float mv[8] = {ma.x, ma.y, ma.z, ma.w, mb.x, mb.y, mb.z, mb.w};

        int myc = 0;
#pragma unroll
        for (int j = 0; j < 8; ++j) myc += (mv[j] != 0.0f);

        int sv = myc;
#pragma unroll
        for (int off = 1; off < 64; off <<= 1) {
            int t = __shfl_up(sv, off, 64);
            if (lane >= off) sv += t;
        }
        if (lane == 63) wsum4[wwid] = (unsigned int)sv;
        __syncthreads();
        int base = 0;
        for (int ww = 0; ww < wwid; ++ww) base += (int)wsum4[ww];
        const int incl = sv + base;
        const int excl = incl - myc;
        if (tid == 255) s_cnt = incl;

        int p = excl;
#pragma unroll
        for (int j = 0; j < 8; ++j) {
            if (mv[j] != 0.0f) {
                if (p < MAXK) {
                    int idx = (j < 4) ? 4 * tid + j : 1024 + 4 * tid + (j - 4);
                    slist[p] = make_int2(idx, __float_as_int(wv[j]));
                }
                ++p;
            }
        }
        __syncthreads();  // slist/s_cnt visible block-wide before phase 2
    } else {
        // ------------- phase 1b: median + gate + transpose-write -------------
        const int b = bid - N_OUT;
        const float4* xr = (const float4*)(x + (size_t)b * N_IN);
        float4 va = xr[tid], vb = xr[tid + 256];
        float vals[8] = {va.x, va.y, va.z, va.w, vb.x, vb.y, vb.z, vb.w};

        unsigned int prefix = 0;
        unsigned int k = (N_IN - 1) / 2;  // 1023: lower-median rank
        for (int pos = 24; pos >= 0; pos -= 8) {
            hist[tid] = 0;
            __syncthreads();
            const unsigned int hmask = (pos == 24) ? 0u : (0xFFFFFFFFu << (pos + 8));
#pragma unroll
            for (int j = 0; j < 8; ++j) {
                unsigned int u = f2key(vals[j]);
                if ((u & hmask) == (prefix & hmask))
                    atomicAdd(&hist[(u >> pos) & 0xFFu], 1u);
            }
            __syncthreads();
            unsigned int v = hist[tid];
            unsigned int sv = v;
#pragma unroll
            for (int off = 1; off < 64; off <<= 1) {
                unsigned int t = __shfl_up(sv, off, 64);
                if (lane >= off) sv += t;
            }
            if (lane == 63) wsum4[wwid] = sv;
            __syncthreads();
            unsigned int base = 0;
            for (int ww = 0; ww < wwid; ++ww) base += wsum4[ww];
            const unsigned int incl = sv + base;
            const unsigned int excl = incl - v;
            if (k >= excl && k < incl) {
                sel[0] = (unsigned int)tid;
                sel[1] = k - excl;
            }
            __syncthreads();
            prefix |= sel[0] << pos;
            k = sel[1];
            __syncthreads();
        }
        const float med = key2f(prefix);

#pragma unroll
        for (int j = 0; j < 8; ++j) {
            const int idx = (j < 4) ? 4 * tid + j : 1024 + 4 * tid + (j - 4);
            const float v = vals[j];
            gxT[(size_t)idx * BATCH + b] = (fabsf(v - med) < 1.0f) ? v : 0.0f;
        }
    }

    cg::this_grid().sync();

    // ---------------- phase 2: sparse LSE, one thread per batch ----------------
    if (bid < N_OUT && tid < BATCH) {
        const int o = bid;
        const int b = tid;
        const int c = s_cnt;
        float res;
        if (c == 0) {
            res = NEG_FILL;  // T*(-1e10 + log 2048) rounds to -1e9 in f32
        } else if (c <= MAXK) {
            int2 e = slist[0];
            float m = (gxT[(size_t)e.x * BATCH + b] + __int_as_float(e.y)) * INV_TEMP;
            float s = 1.0f;
            for (int j = 1; j < c; ++j) {  // c is wave-uniform; gathers coalesced
                e = slist[j];
                float v = (gxT[(size_t)e.x * BATCH + b] + __int_as_float(e.y)) * INV_TEMP;
                float mn = fmaxf(m, v);
                s = s * __expf(m - mn) + __expf(v - mn);
                m = mn;
            }
            res = TEMP * (m + __logf(s));
        } else {
            // overflow fallback (statistically unreachable): dense masked pass
            const float* mr = msk + (size_t)o * N_IN;
            const float* wr = w + (size_t)o * N_IN;
            float m = -INFINITY, s = 0.0f;
            for (int i = 0; i < N_IN; ++i) {
                if (mr[i] != 0.0f) {
                    float v = (gxT[(size_t)i * BATCH + b] + wr[i]) * INV_TEMP;
                    float mn = fmaxf(m, v);
                    s = s * __expf(m - mn) + __expf(v - mn);
                    m = mn;
                }
            }
            res = TEMP * (m + __logf(s));
        }
        out[(size_t)b * N_OUT + o] = res;
    }
}

extern "C" void kernel_launch(void* const* d_in, const int* in_sizes, int n_in,
                              void* d_out, int out_size, void* d_ws, size_t ws_size,
                              hipStream_t stream) {
    const float* x = (const float*)d_in[0];
    const float* w = (const float*)d_in[1];
    const float* msk = (const float*)d_in[2];
    float* out = (float*)d_out;
    float* gxT = (float*)d_ws;  // N_IN * BATCH floats (1 MB), transposed gated x

    void* args[] = {(void*)&x, (void*)&w, (void*)&msk, (void*)&gxT, (void*)&out};
    hipLaunchCooperativeKernel((const void*)k_all, dim3(N_OUT + BATCH), dim3(256),
                               args, 0, stream);
}

// Round 5
// 28.310 us; speedup vs baseline: 5.5424x; 5.5424x over previous
//
#include <hip/hip_runtime.h>
#include <math.h>

#define BATCH 128
#define N_IN 2048
#define N_OUT 1024
#define MAXK 40
#define NCAP 768
#define TEMP 0.1f
#define INV_TEMP 10.0f
#define NEG_FILL -1.0e9f
#define WLO -0.1875f
#define WHI 0.1875f

__device__ __forceinline__ unsigned int f2key(float f) {
    unsigned int b = __float_as_uint(f);
    return (b & 0x80000000u) ? ~b : (b | 0x80000000u);
}
__device__ __forceinline__ float key2f(unsigned int u) {
    unsigned int b = (u & 0x80000000u) ? (u & 0x7FFFFFFFu) : ~u;
    return __uint_as_float(b);
}

// Prep kernel, grid = N_OUT + BATCH.
//  blocks [0, N_OUT): compact row o's actives into entry-major listsT[j][o].
//  blocks [N_OUT, +BATCH): exact lower-median of x row b -> med[b].
//    Fast path: count below WLO + compact candidates in [WLO,WHI) to LDS via
//    shfl-scan (no atomics), then exact rank count among ~300 candidates.
//    Fallback (window miss, statistically unreachable): 4-pass radix select.
__global__ __launch_bounds__(256) void k_prep(const float* __restrict__ x,
                                              const float* __restrict__ w,
                                              const float* __restrict__ msk,
                                              int* __restrict__ cnt,
                                              int2* __restrict__ listsT,
                                              float* __restrict__ med) {
    __shared__ unsigned int wsum4[4];
    __shared__ unsigned int sel[2];
    __shared__ unsigned int hist[256];
    __shared__ float scand[NCAP];
    __shared__ float s_med;

    const int tid = threadIdx.x;
    const int lane = tid & 63;
    const int wwid = tid >> 6;
    const int bid = (int)blockIdx.x;

    if (bid < N_OUT) {
        // ---------------- compaction ----------------
        const int o = bid;
        const float4* wr = (const float4*)(w + (size_t)o * N_IN);
        const float4* mr = (const float4*)(msk + (size_t)o * N_IN);
        float4 wa = wr[tid], wb = wr[tid + 256];
        float4 ma = mr[tid], mb = mr[tid + 256];
        float wv[8] = {wa.x, wa.y, wa.z, wa.w, wb.x, wb.y, wb.z, wb.w};
        float mv[8] = {ma.x, ma.y, ma.z, ma.w, mb.x, mb.y, mb.z, mb.w};

        int myc = 0;
#pragma unroll
        for (int j = 0; j < 8; ++j) myc += (mv[j] != 0.0f);

        int sv = myc;
#pragma unroll
        for (int off = 1; off < 64; off <<= 1) {
            int t = __shfl_up(sv, off, 64);
            if (lane >= off) sv += t;
        }
        if (lane == 63) wsum4[wwid] = (unsigned int)sv;
        __syncthreads();
        int base = 0;
        for (int ww = 0; ww < wwid; ++ww) base += (int)wsum4[ww];
        const int incl = sv + base;
        const int excl = incl - myc;
        if (tid == 255) cnt[o] = incl;

        int p = excl;
#pragma unroll
        for (int j = 0; j < 8; ++j) {
            if (mv[j] != 0.0f) {
                if (p < MAXK) {
                    int idx = (j < 4) ? 4 * tid + j : 1024 + 4 * tid + (j - 4);
                    listsT[p * N_OUT + o] = make_int2(idx, __float_as_int(wv[j]));
                }
                ++p;
            }
        }
    } else {
        // ---------------- exact lower median ----------------
        const int b = bid - N_OUT;
        const float4* xr = (const float4*)(x + (size_t)b * N_IN);
        float4 va = xr[tid], vb = xr[tid + 256];
        float vals[8] = {va.x, va.y, va.z, va.w, vb.x, vb.y, vb.z, vb.w};

        // pass A: count below window, compact in-window candidates
        int cb = 0, cm = 0;
        float cand[8];
#pragma unroll
        for (int j = 0; j < 8; ++j) {
            float v = vals[j];
            cb += (v < WLO) ? 1 : 0;
            if (v >= WLO && v < WHI) cand[cm++] = v;
        }
        int sv = cm;
#pragma unroll
        for (int off = 1; off < 64; off <<= 1) {
            int t = __shfl_up(sv, off, 64);
            if (lane >= off) sv += t;
        }
        if (lane == 63) wsum4[wwid] = (unsigned int)sv;
        __syncthreads();
        int base = 0;
        for (int ww = 0; ww < wwid; ++ww) base += (int)wsum4[ww];
        const int n_c = (int)(wsum4[0] + wsum4[1] + wsum4[2] + wsum4[3]);
        int p = base + sv - cm;
        for (int k = 0; k < cm; ++k) {
            int q = p + k;
            if (q < NCAP) scand[q] = cand[k];
        }
        __syncthreads();  // scand complete; wsum4 free for reuse

        int sb = cb;
#pragma unroll
        for (int off = 1; off < 64; off <<= 1) {
            int t = __shfl_up(sb, off, 64);
            if (lane >= off) sb += t;
        }
        if (lane == 63) wsum4[wwid] = (unsigned int)sb;
        __syncthreads();
        const int c_lo = (int)(wsum4[0] + wsum4[1] + wsum4[2] + wsum4[3]);
        const int r = (N_IN - 1) / 2 - c_lo;  // rank within candidates

        if (r >= 0 && r < n_c && n_c <= NCAP) {
            // exact rank-r among candidates; LDS reads are wave-broadcast
            for (int i = tid; i < n_c; i += 256) {
                float v = scand[i];
                int nlt = 0, neq = 0;
                for (int j = 0; j < n_c; ++j) {
                    float u = scand[j];
                    nlt += (u < v) ? 1 : 0;
                    neq += (u == v) ? 1 : 0;
                }
                if (nlt <= r && r < nlt + neq) s_med = v;  // ties write same value
            }
        } else {
            // fallback: exact 4-pass radix select (unreachable statistically)
            __syncthreads();
            unsigned int prefix = 0;
            unsigned int k = (N_IN - 1) / 2;
            for (int pos = 24; pos >= 0; pos -= 8) {
                hist[tid] = 0;
                __syncthreads();
                const unsigned int hmask = (pos == 24) ? 0u : (0xFFFFFFFFu << (pos + 8));
#pragma unroll
                for (int j = 0; j < 8; ++j) {
                    unsigned int u = f2key(vals[j]);
                    if ((u & hmask) == (prefix & hmask))
                        atomicAdd(&hist[(u >> pos) & 0xFFu], 1u);
                }
                __syncthreads();
                unsigned int v = hist[tid];
                unsigned int s2 = v;
#pragma unroll
                for (int off = 1; off < 64; off <<= 1) {
                    unsigned int t = __shfl_up(s2, off, 64);
                    if (lane >= off) s2 += t;
                }
                if (lane == 63) wsum4[wwid] = s2;
                __syncthreads();
                unsigned int bs = 0;
                for (int ww = 0; ww < wwid; ++ww) bs += wsum4[ww];
                const unsigned int incl = s2 + bs;
                const unsigned int excl = incl - v;
                if (k >= excl && k < incl) {
                    sel[0] = (unsigned int)tid;
                    sel[1] = k - excl;
                }
                __syncthreads();
                prefix |= sel[0] << pos;
                k = sel[1];
                __syncthreads();
            }
            if (tid == 0) s_med = key2f(prefix);
        }
        __syncthreads();
        if (tid == 0) med[b] = s_med;
    }
}

// LSE kernel, grid = BATCH*4: block (b, oq); one output per thread.
__global__ __launch_bounds__(256) void k_lse(const float* __restrict__ x,
                                             const float* __restrict__ medv,
                                             const int* __restrict__ cnt,
                                             const int2* __restrict__ listsT,
                                             const float* __restrict__ w,
                                             const float* __restrict__ msk,
                                             float* __restrict__ out) {
    __shared__ float sgx[N_IN];
    const int b = blockIdx.x >> 2;
    const int oq = blockIdx.x & 3;
    const int tid = threadIdx.x;

    const float med = medv[b];
    const float4* xr = (const float4*)(x + (size_t)b * N_IN);
    float4 va = xr[tid], vb = xr[tid + 256];
    float4 ga, gb;
    ga.x = (fabsf(va.x - med) < 1.0f) ? va.x : 0.0f;
    ga.y = (fabsf(va.y - med) < 1.0f) ? va.y : 0.0f;
    ga.z = (fabsf(va.z - med) < 1.0f) ? va.z : 0.0f;
    ga.w = (fabsf(va.w - med) < 1.0f) ? va.w : 0.0f;
    gb.x = (fabsf(vb.x - med) < 1.0f) ? vb.x : 0.0f;
    gb.y = (fabsf(vb.y - med) < 1.0f) ? vb.y : 0.0f;
    gb.z = (fabsf(vb.z - med) < 1.0f) ? vb.z : 0.0f;
    gb.w = (fabsf(vb.w - med) < 1.0f) ? vb.w : 0.0f;
    ((float4*)sgx)[tid] = ga;
    ((float4*)sgx)[tid + 256] = gb;
    __syncthreads();

    const int o = oq * 256 + tid;
    const int c = cnt[o];
    float res;
    if (c == 0) {
        res = NEG_FILL;  // T*(-1e10 + log 2048) rounds to -1e9 in f32
    } else if (c <= MAXK) {
        float mx = -INFINITY;
        for (int j = 0; j < c; ++j) {  // coalesced: lanes stride 8B at each j
            int2 e = listsT[j * N_OUT + o];
            float v = (sgx[e.x] + __int_as_float(e.y)) * INV_TEMP;
            mx = fmaxf(mx, v);
        }
        float s = 0.0f;
        for (int j = 0; j < c; ++j) {
            int2 e = listsT[j * N_OUT + o];
            float v = (sgx[e.x] + __int_as_float(e.y)) * INV_TEMP;
            s += __expf(v - mx);
        }
        res = TEMP * (mx + __logf(s));
    } else {
        // overflow fallback (statistically unreachable): dense masked pass
        const float* mr = msk + (size_t)o * N_IN;
        const float* wr = w + (size_t)o * N_IN;
        float mx = -INFINITY;
        for (int i = 0; i < N_IN; ++i)
            if (mr[i] != 0.0f) mx = fmaxf(mx, (sgx[i] + wr[i]) * INV_TEMP);
        float s = 0.0f;
        for (int i = 0; i < N_IN; ++i)
            if (mr[i] != 0.0f) s += __expf((sgx[i] + wr[i]) * INV_TEMP - mx);
        res = TEMP * (mx + __logf(s));
    }
    out[(size_t)b * N_OUT + o] = res;
}

extern "C" void kernel_launch(void* const* d_in, const int* in_sizes, int n_in,
                              void* d_out, int out_size, void* d_ws, size_t ws_size,
                              hipStream_t stream) {
    const float* x = (const float*)d_in[0];
    const float* w = (const float*)d_in[1];
    const float* msk = (const float*)d_in[2];
    float* out = (float*)d_out;

    int* cnt = (int*)d_ws;                                // N_OUT ints
    int2* listsT = (int2*)(cnt + N_OUT);                  // MAXK*N_OUT int2 (320 KB)
    float* med = (float*)(listsT + (size_t)MAXK * N_OUT); // BATCH floats

    hipLaunchKernelGGL(k_prep, dim3(N_OUT + BATCH), dim3(256), 0, stream,
                       x, w, msk, cnt, listsT, med);
    hipLaunchKernelGGL(k_lse, dim3(BATCH * 4), dim3(256), 0, stream,
                       x, med, cnt, listsT, w, msk, out);
}